// Round 4
// baseline (738.414 us; speedup 1.0000x reference)
//
#include <hip/hip_runtime.h>
#include <cstdint>
#include <cstddef>

// Problem constants (fixed by the reference)
#define H_DIM 1024
#define I_DIM 4096
#define E_NUM 8
#define TOPK  2
#define T_NUM 4096                 // B*S = 2*2048
#define NROWS (T_NUM * TOPK)       // 8192 assignment rows
#define BK    32                   // K-step in elements (f16 A rows: 64 B; fp32 B rows: 128 B)
#define YMAX  16                   // max 128-row m-tiles per expert (seg<=2048; 34-sigma safe)

typedef _Float16 half8 __attribute__((ext_vector_type(8)));
typedef float    f32x4 __attribute__((ext_vector_type(4)));

// Async global->LDS, 16 B per lane. LDS dest: wave-uniform base + lane*16 (HW rule).
// Global side is per-lane -> supports gathered rows AND source-chunk swizzle.
__device__ __forceinline__ void async_copy16(void* lds, const void* g)
{
    __builtin_amdgcn_global_load_lds(
        (__attribute__((address_space(1))) unsigned int*)g,
        (__attribute__((address_space(3))) unsigned int*)lds,
        16 /*bytes*/, 0 /*offset*/, 0 /*aux*/);
}

// fp32 B tiles: row = 32 f32 = 128 B = 8 x 16B chunks. Swizzle: pos p of row r holds
// global chunk p ^ (r&7). One glds instr covers 8 rows (64 lanes x 16 B); lane rl=lane>>3
// is the row, c=lane&7 the pos -> fetch global chunk c ^ rl. Read side: row fm chunk g
// sits at pos g ^ (fm&7). 16 fragment lanes -> each bank-quad hit exactly 2x = free
// (R2 measured 0 conflicts with this exact 8-chunk scheme).

// B fragment: 8 f32 (chunks 2kq, 2kq+1) -> half8 in-register convert.
__device__ __forceinline__ half8 read_b_frag(const float* __restrict__ Brow, int kq, int sw8)
{
    const f32x4 lo = *(const f32x4*)(Brow + ((((2 * kq)     ^ sw8)) << 2));
    const f32x4 hi = *(const f32x4*)(Brow + ((((2 * kq + 1) ^ sw8)) << 2));
    half8 r;
    r[0] = (_Float16)lo[0]; r[1] = (_Float16)lo[1]; r[2] = (_Float16)lo[2]; r[3] = (_Float16)lo[3];
    r[4] = (_Float16)hi[0]; r[5] = (_Float16)hi[1]; r[6] = (_Float16)hi[2]; r[7] = (_Float16)hi[3];
    return r;
}

// ---------------- fp32 -> fp16 conversion for x only (16 MB read, 8 MB write) ----------------
#define NX4 (T_NUM * H_DIM / 4)
__global__ void cvt_x(const float* __restrict__ x, _Float16* __restrict__ xh)
{
    int i = blockIdx.x * blockDim.x + threadIdx.x;
    if (i >= NX4) return;
    float4 v = reinterpret_cast<const float4*>(x)[i];
    union { _Float16 h[4]; unsigned long long u; } o;
    o.h[0] = (_Float16)v.x; o.h[1] = (_Float16)v.y;
    o.h[2] = (_Float16)v.z; o.h[3] = (_Float16)v.w;
    reinterpret_cast<unsigned long long*>(xh)[i] = o.u;
}

// ---------------- routing: count + prefix + scatter in one block ----------------
__global__ void route_all(const int* __restrict__ ei, const float* __restrict__ ew,
                          int* __restrict__ offs,
                          int* __restrict__ token_of_row, float* __restrict__ weight_of_row)
{
    __shared__ int cnt[E_NUM];
    __shared__ int cur[E_NUM];
    const int t = (int)threadIdx.x;
    if (t < E_NUM) cnt[t] = 0;
    __syncthreads();
    for (int s = t; s < NROWS; s += (int)blockDim.x) atomicAdd(&cnt[ei[s]], 1);
    __syncthreads();
    if (t == 0) {
        int acc = 0;
        for (int e = 0; e < E_NUM; ++e) { offs[e] = acc; cur[e] = acc; acc += cnt[e]; }
        offs[E_NUM] = acc;  // == NROWS
    }
    __syncthreads();
    for (int s = t; s < NROWS; s += (int)blockDim.x) {
        int e = ei[s];
        int r = atomicAdd(&cur[e], 1);
        token_of_row[r]  = s >> 1;   // TOPK = 2
        weight_of_row[r] = ew[s];
    }
}

// ---------------- fused gate+up grouped GEMM + SiLU*mul ----------------
// Tile: 128 rows x 64 cols of I, K = H = 1024, BK = 32. 4 waves (2x2); wave = 64x32 per matrix.
// A (x) staged as f16; B (Wg/Wu) staged as raw fp32 and converted in-register.
__global__ __launch_bounds__(256) void gateup_gemm(
    const _Float16* __restrict__ xh,      // [T][H] f16
    const float*    __restrict__ Wg,      // [E][I][H] fp32
    const float*    __restrict__ Wu,      // [E][I][H] fp32
    const int*      __restrict__ token_of_row,
    const int*      __restrict__ offs,
    _Float16*       __restrict__ inter)   // [NROWS][I] f16
{
    const int e = blockIdx.z;
    const int seg_start = offs[e], seg_end = offs[e + 1];
    const int m0 = seg_start + (int)blockIdx.y * 128;
    if (m0 >= seg_end) return;
    const int n0 = (int)blockIdx.x * 64;

    __shared__ _Float16 Ash[128 * BK];   // 8 KB  (f16, 64-B rows)
    __shared__ float    Bgs[64 * BK];    // 8 KB  (fp32, 128-B rows)
    __shared__ float    Bus[64 * BK];    // 8 KB

    const int tid  = (int)threadIdx.x;
    const int lane = tid & 63, wid = tid >> 6;
    const int wm = wid >> 1, wn = wid & 1;

    // A staging lanes: 16 rows x 4 chunks (64-B rows), with the 4-chunk XOR (harmless)
    const int c4   = lane & 3;
    const int rl16 = lane >> 2;
    const int frl  = (rl16 & 3) ^ (rl16 >> 2);
    const int gc4  = c4 ^ frl;
    // B staging lanes: 8 rows x 8 chunks (128-B rows), proven-zero-conflict 8-chunk XOR
    const int c8  = lane & 7;
    const int rl8 = lane >> 3;
    const int gc8 = c8 ^ rl8;

    // A staging: 8 instrs of 16 rows; this wave does q = 2*wid, 2*wid+1
    const _Float16* pA[2];
    _Float16* lA[2];
#pragma unroll
    for (int j = 0; j < 2; ++j) {
        int q = 2 * wid + j;
        int r = m0 + q * 16 + rl16;
        if (r > seg_end - 1) r = seg_end - 1;       // clamp; garbage rows never stored
        int tok = token_of_row[r];
        pA[j] = xh + (size_t)tok * H_DIM + gc4 * 8;
        lA[j] = &Ash[q * 16 * BK];
    }
    // B staging: 8 instrs each of 8 rows; this wave does q = 2*wid, 2*wid+1
    const float* pBg[2]; const float* pBu[2];
    float* lBg[2]; float* lBu[2];
#pragma unroll
    for (int j = 0; j < 2; ++j) {
        int q = 2 * wid + j;
        int row = q * 8 + rl8;
        pBg[j] = Wg + ((size_t)e * I_DIM + n0 + row) * H_DIM + gc8 * 4;
        pBu[j] = Wu + ((size_t)e * I_DIM + n0 + row) * H_DIM + gc8 * 4;
        lBg[j] = &Bgs[q * 8 * BK];
        lBu[j] = &Bus[q * 8 * BK];
    }

    f32x4 accg[4][2], accu[4][2];
#pragma unroll
    for (int i = 0; i < 4; ++i)
#pragma unroll
        for (int j = 0; j < 2; ++j) {
            accg[i][j] = (f32x4){0.f, 0.f, 0.f, 0.f};
            accu[i][j] = (f32x4){0.f, 0.f, 0.f, 0.f};
        }

    const int fm = lane & 15, kq = lane >> 4;       // kq: 8-elem K-group (0..3)
    const int fswA = (fm & 3) ^ ((fm >> 2) & 3);
    const int rdoA = (kq ^ fswA) * 8;               // A read offset (f16 elems)
    const int sw8  = fm & 7;                        // B read swizzle key

    for (int kt = 0; kt < H_DIM / BK; ++kt) {
        const int ko = kt * BK;
        __syncthreads();                       // protect LDS from overwrite
        async_copy16(lA[0],  pA[0]  + ko);
        async_copy16(lA[1],  pA[1]  + ko);
        async_copy16(lBg[0], pBg[0] + ko);
        async_copy16(lBg[1], pBg[1] + ko);
        async_copy16(lBu[0], pBu[0] + ko);
        async_copy16(lBu[1], pBu[1] + ko);
        __syncthreads();                       // vmcnt(0) drain + visibility

        half8 a[4], bg[2], bu[2];
#pragma unroll
        for (int i = 0; i < 4; ++i)
            a[i] = *(const half8*)&Ash[(wm * 64 + i * 16 + fm) * BK + rdoA];
#pragma unroll
        for (int j = 0; j < 2; ++j) {
            bg[j] = read_b_frag(&Bgs[(wn * 32 + j * 16 + fm) * BK], kq, sw8);
            bu[j] = read_b_frag(&Bus[(wn * 32 + j * 16 + fm) * BK], kq, sw8);
        }
#pragma unroll
        for (int i = 0; i < 4; ++i)
#pragma unroll
            for (int j = 0; j < 2; ++j) {
                accg[i][j] = __builtin_amdgcn_mfma_f32_16x16x32_f16(a[i], bg[j], accg[i][j], 0, 0, 0);
                accu[i][j] = __builtin_amdgcn_mfma_f32_16x16x32_f16(a[i], bu[j], accu[i][j], 0, 0, 0);
            }
    }

    // Epilogue: inter = silu(g) * u, f16 store. C/D: col=lane&15, row=(lane>>4)*4+reg.
#pragma unroll
    for (int i = 0; i < 4; ++i) {
#pragma unroll
        for (int reg = 0; reg < 4; ++reg) {
            int r = m0 + wm * 64 + i * 16 + kq * 4 + reg;
            if (r < seg_end) {
#pragma unroll
                for (int j = 0; j < 2; ++j) {
                    int col = n0 + wn * 32 + j * 16 + fm;
                    float g = accg[i][j][reg];
                    float u = accu[i][j][reg];
                    float sv = (g / (1.f + __expf(-g))) * u;
                    inter[(size_t)r * I_DIM + col] = (_Float16)sv;
                }
            }
        }
    }
}

// ---------------- down grouped GEMM, weighted atomic scatter-add ----------------
// Tile: 128 rows x 128 cols of H, K = I = 4096, BK = 32. Wave = 64x64, acc[4][4].
// A (inter) f16; B (Wd) raw fp32, in-register convert.
__global__ __launch_bounds__(256) void down_gemm(
    const _Float16* __restrict__ inter,   // [NROWS][I] f16
    const float*    __restrict__ Wd,      // [E][H][I] fp32
    const int*      __restrict__ token_of_row,
    const float*    __restrict__ weight_of_row,
    const int*      __restrict__ offs,
    float*          __restrict__ out)     // [T][H], pre-zeroed
{
    const int e = blockIdx.z;
    const int seg_start = offs[e], seg_end = offs[e + 1];
    const int m0 = seg_start + (int)blockIdx.y * 128;
    if (m0 >= seg_end) return;
    const int n0 = (int)blockIdx.x * 128;

    __shared__ _Float16 Ash[128 * BK];   // 8 KB
    __shared__ float    Bsh[128 * BK];   // 16 KB

    const int tid  = (int)threadIdx.x;
    const int lane = tid & 63, wid = tid >> 6;
    const int wm = wid >> 1, wn = wid & 1;

    const int c4   = lane & 3;
    const int rl16 = lane >> 2;
    const int frl  = (rl16 & 3) ^ (rl16 >> 2);
    const int gc4  = c4 ^ frl;
    const int c8  = lane & 7;
    const int rl8 = lane >> 3;
    const int gc8 = c8 ^ rl8;

    const _Float16* pA[2]; _Float16* lA[2];
#pragma unroll
    for (int j = 0; j < 2; ++j) {
        int q = 2 * wid + j;
        int r = m0 + q * 16 + rl16;
        if (r > seg_end - 1) r = seg_end - 1;
        pA[j] = inter + (size_t)r * I_DIM + gc4 * 8;
        lA[j] = &Ash[q * 16 * BK];
    }
    // B: 128 fp32 rows = 16 KB = 16 instrs; this wave does q = 4*wid + 0..3
    const float* pB[4]; float* lB[4];
#pragma unroll
    for (int j = 0; j < 4; ++j) {
        int q = 4 * wid + j;
        int row = q * 8 + rl8;
        pB[j] = Wd + ((size_t)e * H_DIM + n0 + row) * I_DIM + gc8 * 4;
        lB[j] = &Bsh[q * 8 * BK];
    }

    f32x4 acc[4][4];
#pragma unroll
    for (int i = 0; i < 4; ++i)
#pragma unroll
        for (int j = 0; j < 4; ++j) acc[i][j] = (f32x4){0.f, 0.f, 0.f, 0.f};

    const int fm = lane & 15, kq = lane >> 4;
    const int fswA = (fm & 3) ^ ((fm >> 2) & 3);
    const int rdoA = (kq ^ fswA) * 8;
    const int sw8  = fm & 7;

    for (int kt = 0; kt < I_DIM / BK; ++kt) {
        const int ko = kt * BK;
        __syncthreads();
        async_copy16(lA[0], pA[0] + ko);
        async_copy16(lA[1], pA[1] + ko);
#pragma unroll
        for (int j = 0; j < 4; ++j) async_copy16(lB[j], pB[j] + ko);
        __syncthreads();

        half8 a[4], b[4];
#pragma unroll
        for (int i = 0; i < 4; ++i)
            a[i] = *(const half8*)&Ash[(wm * 64 + i * 16 + fm) * BK + rdoA];
#pragma unroll
        for (int j = 0; j < 4; ++j)
            b[j] = read_b_frag(&Bsh[(wn * 64 + j * 16 + fm) * BK], kq, sw8);
#pragma unroll
        for (int i = 0; i < 4; ++i)
#pragma unroll
            for (int j = 0; j < 4; ++j)
                acc[i][j] = __builtin_amdgcn_mfma_f32_16x16x32_f16(a[i], b[j], acc[i][j], 0, 0, 0);
    }

#pragma unroll
    for (int i = 0; i < 4; ++i) {
#pragma unroll
        for (int reg = 0; reg < 4; ++reg) {
            int r = m0 + wm * 64 + i * 16 + kq * 4 + reg;
            if (r < seg_end) {
                float w = weight_of_row[r];
                int   t = token_of_row[r];
#pragma unroll
                for (int j = 0; j < 4; ++j) {
                    int col = n0 + wn * 64 + j * 16 + fm;
                    atomicAdd(&out[(size_t)t * H_DIM + col], w * acc[i][j][reg]);
                }
            }
        }
    }
}

// ---------------- launch ----------------
extern "C" void kernel_launch(void* const* d_in, const int* in_sizes, int n_in,
                              void* d_out, int out_size, void* d_ws, size_t ws_size,
                              hipStream_t stream)
{
    const float* x  = (const float*)d_in[0];
    const int*   ei = (const int*)  d_in[1];
    const float* ew = (const float*)d_in[2];
    const float* gp = (const float*)d_in[3];
    const float* up = (const float*)d_in[4];
    const float* dp = (const float*)d_in[5];
    float* out = (float*)d_out;

    char* ws = (char*)d_ws;
    size_t o = 0;
    _Float16* xh    = (_Float16*)(ws + o); o += (size_t)T_NUM * H_DIM * 2;   // 8 MB
    _Float16* inter = (_Float16*)(ws + o); o += (size_t)NROWS * I_DIM * 2;   // 64 MB
    int*   offs          = (int*)  (ws + o);
    int*   token_of_row  = (int*)  (ws + o + 256);
    float* weight_of_row = (float*)(ws + o + 256 + (size_t)NROWS * 4);
    size_t ws_need = o + 256 + (size_t)NROWS * 8;
    if (ws_size < ws_need) return;  // diagnostic: absmax will equal |ref|max (~2.16)

    hipMemsetAsync(d_out, 0, (size_t)out_size * sizeof(float), stream);

    const int nt = 256;
    cvt_x<<<(NX4 + nt - 1) / nt, nt, 0, stream>>>(x, xh);

    route_all<<<1, 1024, 0, stream>>>(ei, ew, offs, token_of_row, weight_of_row);

    gateup_gemm<<<dim3(I_DIM / 64, YMAX, E_NUM), 256, 0, stream>>>(
        xh, gp, up, token_of_row, offs, inter);
    down_gemm<<<dim3(H_DIM / 128, YMAX, E_NUM), 256, 0, stream>>>(
        inter, dp, token_of_row, weight_of_row, offs, out);
}